// Round 1
// baseline (293.674 us; speedup 1.0000x reference)
//
#include <hip/hip_runtime.h>

namespace {
constexpr int L_ = 512;
constexpr int B_ = 1024;
constexpr int K_ = 64;
constexpr int START_I = 62;
constexpr int STOP_I = 63;
}

__device__ __forceinline__ float bcast0(float x) {
    return __int_as_float(__builtin_amdgcn_readfirstlane(__float_as_int(x)));
}

// One step of the forward recursion.
// Uses EREG as this step's emit value, then reloads EREG with emit for step TNEXT
// (prefetch distance 4). r = per-lane score relative to wave-scalar 'base'.
#define CRF_STEP(EREG, TNEXT)                                               \
    do {                                                                    \
        float ecur = EREG;                                                  \
        {                                                                   \
            int tp = (TNEXT) < len ? (TNEXT) : (len - 1);                   \
            EREG = eb[(long)tp * (B_ * K_)];                                \
        }                                                                   \
        float p = exp2f(r * 1.4426950408889634f);                           \
        __builtin_amdgcn_wave_barrier();                                    \
        pw[lane] = p;                                                       \
        __builtin_amdgcn_wave_barrier();                                    \
        float s0 = 0.f, s1 = 0.f, s2 = 0.f, s3 = 0.f;                       \
        _Pragma("unroll")                                                   \
        for (int jj = 0; jj < 16; ++jj) {                                   \
            float4 pv = *reinterpret_cast<const float4*>(pw + 4 * jj);      \
            s0 = fmaf(Erow[4 * jj + 0], pv.x, s0);                          \
            s1 = fmaf(Erow[4 * jj + 1], pv.y, s1);                          \
            s2 = fmaf(Erow[4 * jj + 2], pv.z, s2);                          \
            s3 = fmaf(Erow[4 * jj + 3], pv.w, s3);                          \
        }                                                                   \
        __builtin_amdgcn_wave_barrier();                                    \
        float s = (s0 + s1) + (s2 + s3);                                    \
        float rn = fmaf(log2f(s), 0.6931471805599453f, ecur);               \
        float c0 = bcast0(rn);                                              \
        r = rn - c0;                                                        \
        base += c0;                                                         \
    } while (0)

__global__ __launch_bounds__(256) void crf_kernel(
    const float* __restrict__ emit,    // (L,B,K)
    const float* __restrict__ trans,   // (K,K)
    const int* __restrict__ labels,    // (L,B)
    const float* __restrict__ masks,   // (L,B)
    float* __restrict__ out)           // (B,)
{
    __shared__ float pbuf[4][K_];
    const int lane = threadIdx.x & 63;
    const int wid = threadIdx.x >> 6;
    const int b = (blockIdx.x << 2) + wid;
    constexpr float LOG2E = 1.4426950408889634f;
    constexpr float LN2 = 0.6931471805599453f;

    // Lane i holds row i of E = exp(T): Erow[j] = exp(T[i][j])
    float Erow[K_];
    {
        const float4* t4 = reinterpret_cast<const float4*>(trans + lane * K_);
        #pragma unroll
        for (int q = 0; q < K_ / 4; ++q) {
            float4 v = t4[q];
            Erow[4 * q + 0] = exp2f(v.x * LOG2E);
            Erow[4 * q + 1] = exp2f(v.y * LOG2E);
            Erow[4 * q + 2] = exp2f(v.z * LOG2E);
            Erow[4 * q + 3] = exp2f(v.w * LOG2E);
        }
    }

    // len[b] = sum_t masks[t,b]  (masks are prefix masks: arange(L) < length)
    int len = 0;
    #pragma unroll
    for (int c = 0; c < L_ / 64; ++c)
        len += (int)masks[(c * 64 + lane) * B_ + b];
    #pragma unroll
    for (int off = 32; off >= 1; off >>= 1)
        len += __shfl_xor(len, off);

    // forward recursion state: score_i = base + r_i
    float r = (lane == START_I) ? 0.0f : -10000.0f;
    float base = 0.0f;
    float* pw = pbuf[wid];
    const float* eb = emit + b * K_ + lane;

    // prefetch emit for t=0..3 (len >= 128 always)
    float e0 = eb[0L * (B_ * K_)];
    float e1 = eb[1L * (B_ * K_)];
    float e2 = eb[2L * (B_ * K_)];
    float e3 = eb[3L * (B_ * K_)];

    int t = 0;
    for (; t + 4 <= len; t += 4) {
        CRF_STEP(e0, t + 4);
        CRF_STEP(e1, t + 5);
        CRF_STEP(e2, t + 6);
        CRF_STEP(e3, t + 7);
    }
    if (t < len) { CRF_STEP(e0, len - 1); ++t; }
    if (t < len) { CRF_STEP(e1, len - 1); ++t; }
    if (t < len) { CRF_STEP(e2, len - 1); ++t; }

    // partition = LSE_k(score_k + T[STOP,k])
    float v = base + r + trans[STOP_I * K_ + lane];
    float M = v;
    #pragma unroll
    for (int off = 32; off >= 1; off >>= 1)
        M = fmaxf(M, __shfl_xor(M, off));
    float pe = exp2f((v - M) * LOG2E);
    #pragma unroll
    for (int off = 32; off >= 1; off >>= 1)
        pe += __shfl_xor(pe, off);
    float part = fmaf(log2f(pe), LN2, M);

    // gold score: lanes cover t = c*64 + lane
    float g = 0.0f;
    #pragma unroll
    for (int c = 0; c < L_ / 64; ++c) {
        int tt = c * 64 + lane;
        if (tt < len) {
            int lt = labels[tt * B_ + b];
            int lp;
            if (tt == 0) lp = START_I;
            else lp = labels[(tt - 1) * B_ + b];
            g += trans[lt * K_ + lp] + emit[((long)tt * B_ + b) * K_ + lt];
        }
    }
    #pragma unroll
    for (int off = 32; off >= 1; off >>= 1)
        g += __shfl_xor(g, off);
    int lastl = labels[(len - 1) * B_ + b];
    g += trans[STOP_I * K_ + lastl];

    if (lane == 0) out[b] = part - g;
}

extern "C" void kernel_launch(void* const* d_in, const int* in_sizes, int n_in,
                              void* d_out, int out_size, void* d_ws, size_t ws_size,
                              hipStream_t stream) {
    const float* emit = (const float*)d_in[0];
    const float* trans = (const float*)d_in[1];
    const int* labels = (const int*)d_in[2];
    const float* masks = (const float*)d_in[3];
    float* out = (float*)d_out;
    crf_kernel<<<B_ / 4, 256, 0, stream>>>(emit, trans, labels, masks, out);
}

// Round 2
// 204.210 us; speedup vs baseline: 1.4381x; 1.4381x over previous
//
#include <hip/hip_runtime.h>

namespace {
constexpr int L_ = 512;
constexpr int B_ = 1024;
constexpr int K_ = 64;
constexpr int START_I = 62;
constexpr int STOP_I = 63;
}

typedef float v2f __attribute__((ext_vector_type(2)));

__device__ __forceinline__ float bcast0(float x) {
    return __int_as_float(__builtin_amdgcn_readfirstlane(__float_as_int(x)));
}

// One step of the forward recursion.
// Uses EREG as this step's emit value, then reloads EREG with emit for step
// TNEXT (prefetch distance 4). r = per-lane score relative to wave-scalar
// 'base'. NORM=1: recenter r around lane0's value (needed every <=4 steps to
// keep exp2 in f32 range; growth <= ~12/step, spread <= ~16).
#define CRF_STEP(EREG, TNEXT, NORM)                                         \
    do {                                                                    \
        float ecur = EREG;                                                  \
        {                                                                   \
            int tp = (TNEXT) < len ? (TNEXT) : (len - 1);                   \
            EREG = eb[(long)tp * (B_ * K_)];                                \
        }                                                                   \
        float p = exp2f(r * 1.4426950408889634f);                           \
        __builtin_amdgcn_wave_barrier();                                    \
        pw[lane] = p;                                                       \
        __builtin_amdgcn_wave_barrier();                                    \
        v2f a0 = {0.f, 0.f}, a1 = {0.f, 0.f};                               \
        v2f a2 = {0.f, 0.f}, a3 = {0.f, 0.f};                               \
        _Pragma("unroll")                                                   \
        for (int q = 0; q < 8; ++q) {                                       \
            float4 pv0 = *reinterpret_cast<const float4*>(pw + 8 * q);      \
            float4 pv1 = *reinterpret_cast<const float4*>(pw + 8 * q + 4);  \
            a0 += E2[4 * q + 0] * (v2f){pv0.x, pv0.y};                      \
            a1 += E2[4 * q + 1] * (v2f){pv0.z, pv0.w};                      \
            a2 += E2[4 * q + 2] * (v2f){pv1.x, pv1.y};                      \
            a3 += E2[4 * q + 3] * (v2f){pv1.z, pv1.w};                      \
        }                                                                   \
        __builtin_amdgcn_wave_barrier();                                    \
        v2f av = (a0 + a1) + (a2 + a3);                                     \
        float s = av.x + av.y;                                              \
        float rn = fmaf(log2f(s), 0.6931471805599453f, ecur);               \
        if (NORM) {                                                         \
            float c0 = bcast0(rn);                                          \
            r = rn - c0;                                                    \
            base += c0;                                                     \
        } else {                                                            \
            r = rn;                                                         \
        }                                                                   \
    } while (0)

__global__ __launch_bounds__(256, 1) void crf_kernel(
    const float* __restrict__ emit,    // (L,B,K)
    const float* __restrict__ trans,   // (K,K)
    const int* __restrict__ labels,    // (L,B)
    const float* __restrict__ masks,   // (L,B)
    float* __restrict__ out)           // (B,)
{
    __shared__ __align__(16) float pbuf[4][K_];
    const int lane = threadIdx.x & 63;
    const int wid = threadIdx.x >> 6;
    const int b = (blockIdx.x << 2) + wid;
    constexpr float LOG2E = 1.4426950408889634f;
    constexpr float LN2 = 0.6931471805599453f;

    // Lane i holds row i of E = exp(T) as 32 packed v2f (64 VGPRs).
    v2f E2[K_ / 2];
    {
        const float4* t4 = reinterpret_cast<const float4*>(trans + lane * K_);
        #pragma unroll
        for (int q = 0; q < K_ / 4; ++q) {
            float4 v = t4[q];
            E2[2 * q + 0] = (v2f){exp2f(v.x * LOG2E), exp2f(v.y * LOG2E)};
            E2[2 * q + 1] = (v2f){exp2f(v.z * LOG2E), exp2f(v.w * LOG2E)};
        }
    }

    // len[b] = sum_t masks[t,b]  (masks are prefix masks: arange(L) < length)
    int len = 0;
    #pragma unroll
    for (int c = 0; c < L_ / 64; ++c)
        len += (int)masks[(c * 64 + lane) * B_ + b];
    #pragma unroll
    for (int off = 32; off >= 1; off >>= 1)
        len += __shfl_xor(len, off);

    // forward recursion state: score_i = base + r_i
    float r = (lane == START_I) ? 0.0f : -10000.0f;
    float base = 0.0f;
    float* pw = pbuf[wid];
    const float* eb = emit + b * K_ + lane;

    // prefetch emit for t=0..3 (len >= 128 always)
    float e0 = eb[0L * (B_ * K_)];
    float e1 = eb[1L * (B_ * K_)];
    float e2 = eb[2L * (B_ * K_)];
    float e3 = eb[3L * (B_ * K_)];

    int t = 0;
    for (; t + 4 <= len; t += 4) {
        CRF_STEP(e0, t + 4, 0);
        CRF_STEP(e1, t + 5, 0);
        CRF_STEP(e2, t + 6, 0);
        CRF_STEP(e3, t + 7, 1);
    }
    // Tail (<=3 steps, no recenter needed: final LSE subtracts the max).
    if (t < len) { CRF_STEP(e0, len - 1, 0); ++t; }
    if (t < len) { CRF_STEP(e1, len - 1, 0); ++t; }
    if (t < len) { CRF_STEP(e2, len - 1, 0); ++t; }

    // partition = LSE_k(score_k + T[STOP,k])
    float v = base + r + trans[STOP_I * K_ + lane];
    float M = v;
    #pragma unroll
    for (int off = 32; off >= 1; off >>= 1)
        M = fmaxf(M, __shfl_xor(M, off));
    float pe = exp2f((v - M) * LOG2E);
    #pragma unroll
    for (int off = 32; off >= 1; off >>= 1)
        pe += __shfl_xor(pe, off);
    float part = fmaf(log2f(pe), LN2, M);

    // gold score: lanes cover t = c*64 + lane
    float g = 0.0f;
    #pragma unroll
    for (int c = 0; c < L_ / 64; ++c) {
        int tt = c * 64 + lane;
        if (tt < len) {
            int lt = labels[tt * B_ + b];
            int lp;
            if (tt == 0) lp = START_I;
            else lp = labels[(tt - 1) * B_ + b];
            g += trans[lt * K_ + lp] + emit[((long)tt * B_ + b) * K_ + lt];
        }
    }
    #pragma unroll
    for (int off = 32; off >= 1; off >>= 1)
        g += __shfl_xor(g, off);
    int lastl = labels[(len - 1) * B_ + b];
    g += trans[STOP_I * K_ + lastl];

    if (lane == 0) out[b] = part - g;
}

extern "C" void kernel_launch(void* const* d_in, const int* in_sizes, int n_in,
                              void* d_out, int out_size, void* d_ws, size_t ws_size,
                              hipStream_t stream) {
    const float* emit = (const float*)d_in[0];
    const float* trans = (const float*)d_in[1];
    const int* labels = (const int*)d_in[2];
    const float* masks = (const float*)d_in[3];
    float* out = (float*)d_out;
    crf_kernel<<<B_ / 4, 256, 0, stream>>>(emit, trans, labels, masks, out);
}

// Round 3
// 190.528 us; speedup vs baseline: 1.5414x; 1.0718x over previous
//
#include <hip/hip_runtime.h>

namespace {
constexpr int L_ = 512;
constexpr int B_ = 1024;
constexpr int K_ = 64;
constexpr int START_I = 62;
constexpr int STOP_I = 63;
}

typedef float v2f __attribute__((ext_vector_type(2)));

__device__ __forceinline__ float bcast0(float x) {
    return __int_as_float(__builtin_amdgcn_readfirstlane(__float_as_int(x)));
}

// Dot-product partial: 2 LDS broadcast b128 reads + 4 packed FMAs.
#define DOT4(q, Ea, Eb, Ec, Ed)                                             \
    {                                                                       \
        float4 pv0 = *reinterpret_cast<const float4*>(pw + 8 * (q));        \
        float4 pv1 = *reinterpret_cast<const float4*>(pw + 8 * (q) + 4);    \
        a0 += Ea * (v2f){pv0.x, pv0.y};                                     \
        a1 += Eb * (v2f){pv0.z, pv0.w};                                     \
        a2 += Ec * (v2f){pv1.x, pv1.y};                                     \
        a3 += Ed * (v2f){pv1.z, pv1.w};                                     \
    }

// One forward-recursion step in the LINEAR domain.
// p' = (sum_j E[i][j] p_j) * exp(emit_i).  ERAW holds emit loaded 8 steps
// ago; its exp2f is computed at step start (off the LDS critical path).
// RECEN: rescale by an exact power of two taken from lane 0's exponent.
#define CRF_STEP(ERAW, TNEXT, RECEN)                                        \
    do {                                                                    \
        pw[lane] = p;                                                       \
        float ee = exp2f(ERAW * 1.4426950408889634f);                       \
        {                                                                   \
            int tp = (TNEXT) < len ? (TNEXT) : (len - 1);                   \
            ERAW = eb[(long)tp * (B_ * K_)];                                \
        }                                                                   \
        __builtin_amdgcn_wave_barrier();                                    \
        v2f a0 = {0.f, 0.f}, a1 = {0.f, 0.f};                               \
        v2f a2 = {0.f, 0.f}, a3 = {0.f, 0.f};                               \
        DOT4(0, E0, E1, E2, E3)                                             \
        DOT4(1, E4, E5, E6, E7)                                             \
        DOT4(2, E8, E9, E10, E11)                                           \
        DOT4(3, E12, E13, E14, E15)                                         \
        DOT4(4, E16, E17, E18, E19)                                         \
        DOT4(5, E20, E21, E22, E23)                                         \
        DOT4(6, E24, E25, E26, E27)                                         \
        DOT4(7, E28, E29, E30, E31)                                         \
        __builtin_amdgcn_wave_barrier();                                    \
        v2f av = (a0 + a1) + (a2 + a3);                                     \
        float pn = (av.x + av.y) * ee;                                      \
        if (RECEN) {                                                        \
            float p0 = bcast0(pn);                                          \
            int k = (int)(__float_as_uint(p0) >> 23) - 127;                 \
            float scale = __uint_as_float((unsigned)(127 - k) << 23);       \
            pn *= scale;                                                    \
            base2 += (float)k;                                              \
        }                                                                   \
        p = pn;                                                             \
    } while (0)

__global__ __launch_bounds__(256, 1) void crf_kernel(
    const float* __restrict__ emit,    // (L,B,K)
    const float* __restrict__ trans,   // (K,K)
    const int* __restrict__ labels,    // (L,B)
    const float* __restrict__ masks,   // (L,B)
    float* __restrict__ out)           // (B,)
{
    __shared__ __align__(16) float pbuf[4][K_];
    const int lane = threadIdx.x & 63;
    const int wid = threadIdx.x >> 6;
    const int b = (blockIdx.x << 2) + wid;
    constexpr float LOG2E = 1.4426950408889634f;
    constexpr float LN2 = 0.6931471805599453f;

    // E = exp(T), row `lane`, in 32 NAMED v2f SSA values (never an alloca,
    // so it can't be demoted to scratch).
    const float4* t4 = reinterpret_cast<const float4*>(trans + lane * K_);
#define MKE(q, ea, eb_)                                                     \
    float4 tv##q = t4[q];                                                   \
    v2f E##ea = {exp2f(tv##q.x * LOG2E), exp2f(tv##q.y * LOG2E)};           \
    v2f E##eb_ = {exp2f(tv##q.z * LOG2E), exp2f(tv##q.w * LOG2E)};
    MKE(0, 0, 1)   MKE(1, 2, 3)   MKE(2, 4, 5)   MKE(3, 6, 7)
    MKE(4, 8, 9)   MKE(5, 10, 11) MKE(6, 12, 13) MKE(7, 14, 15)
    MKE(8, 16, 17) MKE(9, 18, 19) MKE(10, 20, 21) MKE(11, 22, 23)
    MKE(12, 24, 25) MKE(13, 26, 27) MKE(14, 28, 29) MKE(15, 30, 31)
#undef MKE

    // len[b] = sum_t masks[t,b]  (masks are prefix masks)
    int len = 0;
    #pragma unroll
    for (int c = 0; c < L_ / 64; ++c)
        len += (int)masks[(c * 64 + lane) * B_ + b];
    #pragma unroll
    for (int off = 32; off >= 1; off >>= 1)
        len += __shfl_xor(len, off);

    // Linear-domain state: score_i = log2(p_i)*ln2 ... tracked as
    // p (per-lane) and base2 (wave-uniform accumulated exponent, log2 units).
    float p = (lane == START_I) ? 1.0f : 0.0f;
    float base2 = 0.0f;
    float* pw = pbuf[wid];
    const float* eb = emit + b * K_ + lane;

    // 8-deep emit prefetch ring (len >= 128 always).
    float e0 = eb[0L * (B_ * K_)];
    float e1 = eb[1L * (B_ * K_)];
    float e2 = eb[2L * (B_ * K_)];
    float e3 = eb[3L * (B_ * K_)];
    float e4 = eb[4L * (B_ * K_)];
    float e5 = eb[5L * (B_ * K_)];
    float e6 = eb[6L * (B_ * K_)];
    float e7 = eb[7L * (B_ * K_)];

    int t = 0;
    for (; t + 8 <= len; t += 8) {
        CRF_STEP(e0, t + 8, 0);
        CRF_STEP(e1, t + 9, 0);
        CRF_STEP(e2, t + 10, 0);
        CRF_STEP(e3, t + 11, 1);
        CRF_STEP(e4, t + 12, 0);
        CRF_STEP(e5, t + 13, 0);
        CRF_STEP(e6, t + 14, 0);
        CRF_STEP(e7, t + 15, 1);
    }
    // Tail (<=7 steps); recenter every step (cheap, keeps range bounded).
    if (t < len) { CRF_STEP(e0, len - 1, 1); ++t; }
    if (t < len) { CRF_STEP(e1, len - 1, 1); ++t; }
    if (t < len) { CRF_STEP(e2, len - 1, 1); ++t; }
    if (t < len) { CRF_STEP(e3, len - 1, 1); ++t; }
    if (t < len) { CRF_STEP(e4, len - 1, 1); ++t; }
    if (t < len) { CRF_STEP(e5, len - 1, 1); ++t; }
    if (t < len) { CRF_STEP(e6, len - 1, 1); ++t; }

    // partition = LSE_k(score_k + T[STOP,k]),  score_k = (log2 p_k + base2)*ln2
    float v = fmaf(__log2f(p) + base2, LN2, trans[STOP_I * K_ + lane]);
    float M = v;
    #pragma unroll
    for (int off = 32; off >= 1; off >>= 1)
        M = fmaxf(M, __shfl_xor(M, off));
    float pe = exp2f((v - M) * LOG2E);
    #pragma unroll
    for (int off = 32; off >= 1; off >>= 1)
        pe += __shfl_xor(pe, off);
    float part = fmaf(__log2f(pe), LN2, M);

    // gold score: lanes cover t = c*64 + lane
    float g = 0.0f;
    #pragma unroll
    for (int c = 0; c < L_ / 64; ++c) {
        int tt = c * 64 + lane;
        if (tt < len) {
            int lt = labels[tt * B_ + b];
            int lp;
            if (tt == 0) lp = START_I;
            else lp = labels[(tt - 1) * B_ + b];
            g += trans[lt * K_ + lp] + emit[((long)tt * B_ + b) * K_ + lt];
        }
    }
    #pragma unroll
    for (int off = 32; off >= 1; off >>= 1)
        g += __shfl_xor(g, off);
    int lastl = labels[(len - 1) * B_ + b];
    g += trans[STOP_I * K_ + lastl];

    if (lane == 0) out[b] = part - g;
}

extern "C" void kernel_launch(void* const* d_in, const int* in_sizes, int n_in,
                              void* d_out, int out_size, void* d_ws, size_t ws_size,
                              hipStream_t stream) {
    const float* emit = (const float*)d_in[0];
    const float* trans = (const float*)d_in[1];
    const int* labels = (const int*)d_in[2];
    const float* masks = (const float*)d_in[3];
    float* out = (float*)d_out;
    crf_kernel<<<B_ / 4, 256, 0, stream>>>(emit, trans, labels, masks, out);
}

// Round 4
// 190.346 us; speedup vs baseline: 1.5428x; 1.0010x over previous
//
#include <hip/hip_runtime.h>

namespace {
constexpr int L_ = 512;
constexpr int B_ = 1024;
constexpr int K_ = 64;
constexpr int START_I = 62;
constexpr int STOP_I = 63;
}

typedef float v2f __attribute__((ext_vector_type(2)));

__device__ __forceinline__ float bcast0(float x) {
    return __int_as_float(__builtin_amdgcn_readfirstlane(__float_as_int(x)));
}

// Dot-product partial: 2 LDS broadcast b128 reads + 4 packed FMAs.
#define DOT4(q, Ea, Eb, Ec, Ed)                                             \
    {                                                                       \
        float4 pv0 = *reinterpret_cast<const float4*>(pw + 8 * (q));        \
        float4 pv1 = *reinterpret_cast<const float4*>(pw + 8 * (q) + 4);    \
        a0 += Ea * (v2f){pv0.x, pv0.y};                                     \
        a1 += Eb * (v2f){pv0.z, pv0.w};                                     \
        a2 += Ec * (v2f){pv1.x, pv1.y};                                     \
        a3 += Ed * (v2f){pv1.z, pv1.w};                                     \
    }

// One forward-recursion step in the LINEAR domain.
// p' = (sum_j E[i][j] p_j) * exp(emit_i).  ERAW holds emit loaded 8 steps
// ago; its exp2f is computed at step start (off the LDS critical path).
// RECEN: rescale by an exact power of two taken from lane 0's exponent.
#define CRF_STEP(ERAW, TNEXT, RECEN)                                        \
    do {                                                                    \
        pw[lane] = p;                                                       \
        float ee = exp2f(ERAW * 1.4426950408889634f);                       \
        {                                                                   \
            int tp = (TNEXT) < len ? (TNEXT) : (len - 1);                   \
            ERAW = eb[(long)tp * (B_ * K_)];                                \
        }                                                                   \
        __builtin_amdgcn_wave_barrier();                                    \
        v2f a0 = {0.f, 0.f}, a1 = {0.f, 0.f};                               \
        v2f a2 = {0.f, 0.f}, a3 = {0.f, 0.f};                               \
        DOT4(0, E0, E1, E2, E3)                                             \
        DOT4(1, E4, E5, E6, E7)                                             \
        DOT4(2, E8, E9, E10, E11)                                           \
        DOT4(3, E12, E13, E14, E15)                                         \
        DOT4(4, E16, E17, E18, E19)                                         \
        DOT4(5, E20, E21, E22, E23)                                         \
        DOT4(6, E24, E25, E26, E27)                                         \
        DOT4(7, E28, E29, E30, E31)                                         \
        __builtin_amdgcn_wave_barrier();                                    \
        v2f av = (a0 + a1) + (a2 + a3);                                     \
        float pn = (av.x + av.y) * ee;                                      \
        if (RECEN) {                                                        \
            float p0 = bcast0(pn);                                          \
            int k = (int)(__float_as_uint(p0) >> 23) - 127;                 \
            float scale = __uint_as_float((unsigned)(127 - k) << 23);       \
            pn *= scale;                                                    \
            base2 += (float)k;                                              \
        }                                                                   \
        p = pn;                                                             \
    } while (0)

__global__ __launch_bounds__(256, 1) void crf_kernel(
    const float* __restrict__ emit,    // (L,B,K)
    const float* __restrict__ trans,   // (K,K)
    const int* __restrict__ labels,    // (L,B)
    const float* __restrict__ masks,   // (L,B)
    float* __restrict__ out)           // (B,)
{
    __shared__ __align__(16) float pbuf[4][K_];
    const int lane = threadIdx.x & 63;
    const int wid = threadIdx.x >> 6;
    const int b = (blockIdx.x << 2) + wid;
    constexpr float LOG2E = 1.4426950408889634f;
    constexpr float LN2 = 0.6931471805599453f;

    // E = exp(T), row `lane`, in 32 named v2f values. Each is laundered
    // through inline asm so the register allocator CANNOT rematerialize it
    // (v_exp_f32 of an invariant load is otherwise remat'd into the loop,
    // which is what kept VGPR_Count at 60 and ~890 cyc/step in R2/R3).
    const float4* t4 = reinterpret_cast<const float4*>(trans + lane * K_);
#define MKE(q, ea, eb_)                                                     \
    float4 tv##q = t4[q];                                                   \
    v2f E##ea = {exp2f(tv##q.x * LOG2E), exp2f(tv##q.y * LOG2E)};           \
    v2f E##eb_ = {exp2f(tv##q.z * LOG2E), exp2f(tv##q.w * LOG2E)};          \
    asm volatile("" : "+v"(E##ea));                                         \
    asm volatile("" : "+v"(E##eb_));
    MKE(0, 0, 1)   MKE(1, 2, 3)   MKE(2, 4, 5)   MKE(3, 6, 7)
    MKE(4, 8, 9)   MKE(5, 10, 11) MKE(6, 12, 13) MKE(7, 14, 15)
    MKE(8, 16, 17) MKE(9, 18, 19) MKE(10, 20, 21) MKE(11, 22, 23)
    MKE(12, 24, 25) MKE(13, 26, 27) MKE(14, 28, 29) MKE(15, 30, 31)
#undef MKE

    // len[b] = sum_t masks[t,b]  (masks are prefix masks)
    int len = 0;
    #pragma unroll
    for (int c = 0; c < L_ / 64; ++c)
        len += (int)masks[(c * 64 + lane) * B_ + b];
    #pragma unroll
    for (int off = 32; off >= 1; off >>= 1)
        len += __shfl_xor(len, off);

    // Linear-domain state: score_i = (log2 p_i + base2)*ln2, tracked as
    // p (per-lane) and base2 (wave-uniform accumulated exponent, log2 units).
    float p = (lane == START_I) ? 1.0f : 0.0f;
    float base2 = 0.0f;
    float* pw = pbuf[wid];
    const float* eb = emit + b * K_ + lane;

    // 8-deep emit prefetch ring (len >= 128 always).
    float e0 = eb[0L * (B_ * K_)];
    float e1 = eb[1L * (B_ * K_)];
    float e2 = eb[2L * (B_ * K_)];
    float e3 = eb[3L * (B_ * K_)];
    float e4 = eb[4L * (B_ * K_)];
    float e5 = eb[5L * (B_ * K_)];
    float e6 = eb[6L * (B_ * K_)];
    float e7 = eb[7L * (B_ * K_)];

    int t = 0;
    for (; t + 8 <= len; t += 8) {
        CRF_STEP(e0, t + 8, 0);
        CRF_STEP(e1, t + 9, 0);
        CRF_STEP(e2, t + 10, 0);
        CRF_STEP(e3, t + 11, 1);
        CRF_STEP(e4, t + 12, 0);
        CRF_STEP(e5, t + 13, 0);
        CRF_STEP(e6, t + 14, 0);
        CRF_STEP(e7, t + 15, 1);
    }
    // Tail (<=7 steps); recenter every step (cheap, keeps range bounded).
    if (t < len) { CRF_STEP(e0, len - 1, 1); ++t; }
    if (t < len) { CRF_STEP(e1, len - 1, 1); ++t; }
    if (t < len) { CRF_STEP(e2, len - 1, 1); ++t; }
    if (t < len) { CRF_STEP(e3, len - 1, 1); ++t; }
    if (t < len) { CRF_STEP(e4, len - 1, 1); ++t; }
    if (t < len) { CRF_STEP(e5, len - 1, 1); ++t; }
    if (t < len) { CRF_STEP(e6, len - 1, 1); ++t; }

    // partition = LSE_k(score_k + T[STOP,k]),  score_k = (log2 p_k + base2)*ln2
    float v = fmaf(__log2f(p) + base2, LN2, trans[STOP_I * K_ + lane]);
    float M = v;
    #pragma unroll
    for (int off = 32; off >= 1; off >>= 1)
        M = fmaxf(M, __shfl_xor(M, off));
    float pe = exp2f((v - M) * LOG2E);
    #pragma unroll
    for (int off = 32; off >= 1; off >>= 1)
        pe += __shfl_xor(pe, off);
    float part = fmaf(__log2f(pe), LN2, M);

    // gold score: lanes cover t = c*64 + lane
    float g = 0.0f;
    #pragma unroll
    for (int c = 0; c < L_ / 64; ++c) {
        int tt = c * 64 + lane;
        if (tt < len) {
            int lt = labels[tt * B_ + b];
            int lp;
            if (tt == 0) lp = START_I;
            else lp = labels[(tt - 1) * B_ + b];
            g += trans[lt * K_ + lp] + emit[((long)tt * B_ + b) * K_ + lt];
        }
    }
    #pragma unroll
    for (int off = 32; off >= 1; off >>= 1)
        g += __shfl_xor(g, off);
    int lastl = labels[(len - 1) * B_ + b];
    g += trans[STOP_I * K_ + lastl];

    if (lane == 0) out[b] = part - g;
}

extern "C" void kernel_launch(void* const* d_in, const int* in_sizes, int n_in,
                              void* d_out, int out_size, void* d_ws, size_t ws_size,
                              hipStream_t stream) {
    const float* emit = (const float*)d_in[0];
    const float* trans = (const float*)d_in[1];
    const int* labels = (const int*)d_in[2];
    const float* masks = (const float*)d_in[3];
    float* out = (float*)d_out;
    crf_kernel<<<B_ / 4, 256, 0, stream>>>(emit, trans, labels, masks, out);
}

// Round 5
// 130.486 us; speedup vs baseline: 2.2506x; 1.4588x over previous
//
#include <hip/hip_runtime.h>

namespace {
constexpr int L_ = 512;
constexpr int B_ = 1024;
constexpr int K_ = 64;
constexpr int START_I = 62;
constexpr int STOP_I = 63;
}

__device__ __forceinline__ float bcast0(float x) {
    return __int_as_float(__builtin_amdgcn_readfirstlane(__float_as_int(x)));
}

// 4 MACs: broadcast p_j (j=k..k+3) to SGPRs via v_readlane, then
// v_fmac_f32 vacc, s_pj, vE_j. No LDS, no shared pipe — pure per-SIMD VALU.
#define MAC4(k, Ea, Eb, Ec, Ed)                                             \
    {                                                                       \
        float pa = __int_as_float(__builtin_amdgcn_readlane(pi, (k)));      \
        float pb = __int_as_float(__builtin_amdgcn_readlane(pi, (k) + 1));  \
        float pc = __int_as_float(__builtin_amdgcn_readlane(pi, (k) + 2));  \
        float pd = __int_as_float(__builtin_amdgcn_readlane(pi, (k) + 3));  \
        a0 = fmaf(pa, Ea, a0);                                              \
        a1 = fmaf(pb, Eb, a1);                                              \
        a2 = fmaf(pc, Ec, a2);                                              \
        a3 = fmaf(pd, Ed, a3);                                              \
    }

// One forward-recursion step in the LINEAR domain.
// p'_i = (sum_j E[i][j] p_j) * exp(emit_i). ERAW = emit loaded 4 steps ago.
// RECEN: rescale by an exact power of two from lane 0's exponent (proven R2).
#define CRF_STEP(EREG, TNEXT, RECEN)                                        \
    do {                                                                    \
        float ee = exp2f(EREG * 1.4426950408889634f);                       \
        {                                                                   \
            int tp = (TNEXT) < len ? (TNEXT) : (len - 1);                   \
            EREG = eb[(long)tp * (B_ * K_)];                                \
        }                                                                   \
        int pi = __float_as_int(p);                                         \
        float a0 = 0.f, a1 = 0.f, a2 = 0.f, a3 = 0.f;                       \
        MAC4(0,  E0,  E1,  E2,  E3)   MAC4(4,  E4,  E5,  E6,  E7)           \
        MAC4(8,  E8,  E9,  E10, E11)  MAC4(12, E12, E13, E14, E15)          \
        MAC4(16, E16, E17, E18, E19)  MAC4(20, E20, E21, E22, E23)          \
        MAC4(24, E24, E25, E26, E27)  MAC4(28, E28, E29, E30, E31)          \
        MAC4(32, E32, E33, E34, E35)  MAC4(36, E36, E37, E38, E39)          \
        MAC4(40, E40, E41, E42, E43)  MAC4(44, E44, E45, E46, E47)          \
        MAC4(48, E48, E49, E50, E51)  MAC4(52, E52, E53, E54, E55)          \
        MAC4(56, E56, E57, E58, E59)  MAC4(60, E60, E61, E62, E63)          \
        float pn = ((a0 + a1) + (a2 + a3)) * ee;                            \
        if (RECEN) {                                                        \
            float p0 = bcast0(pn);                                          \
            int kk = (int)(__float_as_uint(p0) >> 23) - 127;                \
            pn *= __uint_as_float((unsigned)(127 - kk) << 23);              \
            base2 += (float)kk;                                             \
        }                                                                   \
        p = pn;                                                             \
    } while (0)

__global__ __launch_bounds__(64)
__attribute__((amdgpu_waves_per_eu(1, 1)))
void crf_kernel(
    const float* __restrict__ emit,    // (L,B,K)
    const float* __restrict__ trans,   // (K,K)
    const int* __restrict__ labels,    // (L,B)
    const float* __restrict__ masks,   // (L,B)
    float* __restrict__ out)           // (B,)
{
    const int lane = threadIdx.x & 63;
    const int b = blockIdx.x;
    constexpr float LOG2E = 1.4426950408889634f;
    constexpr float LN2 = 0.6931471805599453f;

    // E row `lane` of exp(T) in 64 named scalars (targets VGPR residency;
    // amdgpu_waves_per_eu(1,1) gives the allocator the full 512-reg budget
    // and no occupancy incentive to spill/remat).
    const float4* t4 = reinterpret_cast<const float4*>(trans + lane * K_);
#define MKE(q, A, Bn, C, D)                                                 \
    float4 tv##q = t4[q];                                                   \
    float A  = exp2f(tv##q.x * LOG2E);                                      \
    float Bn = exp2f(tv##q.y * LOG2E);                                      \
    float C  = exp2f(tv##q.z * LOG2E);                                      \
    float D  = exp2f(tv##q.w * LOG2E);                                      \
    asm("" : "+v"(A), "+v"(Bn), "+v"(C), "+v"(D));
    MKE(0,  E0,  E1,  E2,  E3)   MKE(1,  E4,  E5,  E6,  E7)
    MKE(2,  E8,  E9,  E10, E11)  MKE(3,  E12, E13, E14, E15)
    MKE(4,  E16, E17, E18, E19)  MKE(5,  E20, E21, E22, E23)
    MKE(6,  E24, E25, E26, E27)  MKE(7,  E28, E29, E30, E31)
    MKE(8,  E32, E33, E34, E35)  MKE(9,  E36, E37, E38, E39)
    MKE(10, E40, E41, E42, E43)  MKE(11, E44, E45, E46, E47)
    MKE(12, E48, E49, E50, E51)  MKE(13, E52, E53, E54, E55)
    MKE(14, E56, E57, E58, E59)  MKE(15, E60, E61, E62, E63)
#undef MKE

    // len[b] = sum_t masks[t,b]  (masks are prefix masks)
    int len = 0;
    #pragma unroll
    for (int c = 0; c < L_ / 64; ++c)
        len += (int)masks[(c * 64 + lane) * B_ + b];
    #pragma unroll
    for (int off = 32; off >= 1; off >>= 1)
        len += __shfl_xor(len, off);

    // Linear-domain state: score_i = (log2 p_i + base2)*ln2.
    float p = (lane == START_I) ? 1.0f : 0.0f;
    float base2 = 0.0f;
    const float* eb = emit + b * K_ + lane;

    // 4-deep emit prefetch ring (len >= 128 always).
    float e0 = eb[0L * (B_ * K_)];
    float e1 = eb[1L * (B_ * K_)];
    float e2 = eb[2L * (B_ * K_)];
    float e3 = eb[3L * (B_ * K_)];

    int t = 0;
    for (; t + 4 <= len; t += 4) {
        CRF_STEP(e0, t + 4, 0);
        CRF_STEP(e1, t + 5, 0);
        CRF_STEP(e2, t + 6, 0);
        CRF_STEP(e3, t + 7, 1);
    }
    if (t < len) { CRF_STEP(e0, len - 1, 1); ++t; }
    if (t < len) { CRF_STEP(e1, len - 1, 1); ++t; }
    if (t < len) { CRF_STEP(e2, len - 1, 1); ++t; }

    // partition = LSE_k(score_k + T[STOP,k])
    float v = fmaf(__log2f(p) + base2, LN2, trans[STOP_I * K_ + lane]);
    float M = v;
    #pragma unroll
    for (int off = 32; off >= 1; off >>= 1)
        M = fmaxf(M, __shfl_xor(M, off));
    float pe = exp2f((v - M) * LOG2E);
    #pragma unroll
    for (int off = 32; off >= 1; off >>= 1)
        pe += __shfl_xor(pe, off);
    float part = fmaf(__log2f(pe), LN2, M);

    // gold score: lanes cover t = c*64 + lane
    float g = 0.0f;
    #pragma unroll
    for (int c = 0; c < L_ / 64; ++c) {
        int tt = c * 64 + lane;
        if (tt < len) {
            int lt = labels[tt * B_ + b];
            int lp;
            if (tt == 0) lp = START_I;
            else lp = labels[(tt - 1) * B_ + b];
            g += trans[lt * K_ + lp] + emit[((long)tt * B_ + b) * K_ + lt];
        }
    }
    #pragma unroll
    for (int off = 32; off >= 1; off >>= 1)
        g += __shfl_xor(g, off);
    int lastl = labels[(len - 1) * B_ + b];
    g += trans[STOP_I * K_ + lastl];

    if (lane == 0) out[b] = part - g;
}

extern "C" void kernel_launch(void* const* d_in, const int* in_sizes, int n_in,
                              void* d_out, int out_size, void* d_ws, size_t ws_size,
                              hipStream_t stream) {
    const float* emit = (const float*)d_in[0];
    const float* trans = (const float*)d_in[1];
    const int* labels = (const int*)d_in[2];
    const float* masks = (const float*)d_in[3];
    float* out = (float*)d_out;
    crf_kernel<<<B_, 64, 0, stream>>>(emit, trans, labels, masks, out);
}